// Round 1
// baseline (100.072 us; speedup 1.0000x reference)
//
#include <hip/hip_runtime.h>

#define VOCAB 32000
#define EMB   1024

// ---------------------------------------------------------------------------
// Kernel 1: transpose W [EMB][VOCAB] -> WT [VOCAB][EMB]
// 64x64 float tile per block, 256 threads, float4 global I/O both sides.
// LDS pitch 65: bank index = (4x + jj + y) mod 32 over the wave -> 2-way
// aliasing only (free on CDNA4).
// ---------------------------------------------------------------------------
__global__ __launch_bounds__(256) void tok_emb_transpose(
    const float* __restrict__ W, float* __restrict__ WT) {
    __shared__ float tile[64][65];

    const int v0 = blockIdx.x * 64;   // vocab tile origin (0..31936)
    const int e0 = blockIdx.y * 64;   // emb tile origin   (0..960)
    const int x  = threadIdx.x & 15;  // 0..15  (float4 column group)
    const int y  = threadIdx.x >> 4;  // 0..15  (row group)

    // Load: W rows e0+y+16k, 64 floats along vocab, coalesced float4.
#pragma unroll
    for (int k = 0; k < 4; ++k) {
        const int el = y + 16 * k;
        const float4 v = *reinterpret_cast<const float4*>(
            &W[(size_t)(e0 + el) * VOCAB + (size_t)(v0 + x * 4)]);
        tile[el][x * 4 + 0] = v.x;
        tile[el][x * 4 + 1] = v.y;
        tile[el][x * 4 + 2] = v.z;
        tile[el][x * 4 + 3] = v.w;
    }
    __syncthreads();

    // Store: WT rows v0+y+16k, 64 floats along emb, coalesced float4.
#pragma unroll
    for (int k = 0; k < 4; ++k) {
        const int vl = y + 16 * k;
        float4 o;
        o.x = tile[x * 4 + 0][vl];
        o.y = tile[x * 4 + 1][vl];
        o.z = tile[x * 4 + 2][vl];
        o.w = tile[x * 4 + 3][vl];
        *reinterpret_cast<float4*>(
            &WT[(size_t)(v0 + vl) * EMB + (size_t)(e0 + x * 4)]) = o;
    }
}

// ---------------------------------------------------------------------------
// Kernel 2: out[t, :] = WT[tokens[t], :]
// One block per token; 256 threads x float4 = 1024 floats.
// tokens[blockIdx.x] is block-uniform -> scalar load; reads/writes coalesced.
// ---------------------------------------------------------------------------
__global__ __launch_bounds__(256) void tok_emb_gather(
    const float4* __restrict__ WT4, const int* __restrict__ tokens,
    float4* __restrict__ out4) {
    const int t   = blockIdx.x;
    const int tok = tokens[t];
    out4[(size_t)t * 256 + threadIdx.x] =
        WT4[(size_t)tok * 256 + threadIdx.x];
}

// ---------------------------------------------------------------------------
// Fallback (ws too small for WT): direct column gather, uncoalesced reads.
// ---------------------------------------------------------------------------
__global__ __launch_bounds__(256) void tok_emb_direct(
    const float* __restrict__ W, const int* __restrict__ tokens,
    float* __restrict__ out) {
    const int t   = blockIdx.x;
    const int tok = tokens[t];
    for (int e = threadIdx.x; e < EMB; e += 256) {
        out[(size_t)t * EMB + e] = W[(size_t)e * VOCAB + tok];
    }
}

extern "C" void kernel_launch(void* const* d_in, const int* in_sizes, int n_in,
                              void* d_out, int out_size, void* d_ws, size_t ws_size,
                              hipStream_t stream) {
    const int*   tokens   = (const int*)d_in[0];   // [8*4096] int32
    const float* W        = (const float*)d_in[1]; // [1024][32000] f32
    float*       out      = (float*)d_out;         // [32768][1024] f32
    const int    n_tokens = in_sizes[0];

    const size_t wt_bytes = (size_t)VOCAB * EMB * sizeof(float);

    if (ws_size >= wt_bytes) {
        float* WT = (float*)d_ws;
        dim3 tgrid(VOCAB / 64, EMB / 64);  // 500 x 16
        tok_emb_transpose<<<tgrid, 256, 0, stream>>>(W, WT);
        tok_emb_gather<<<n_tokens, 256, 0, stream>>>(
            (const float4*)WT, tokens, (float4*)out);
    } else {
        tok_emb_direct<<<n_tokens, 256, 0, stream>>>(W, tokens, out);
    }
}

// Round 3
// 59.312 us; speedup vs baseline: 1.6872x; 1.6872x over previous
//
#include <hip/hip_runtime.h>

#define VOCAB 32000
#define EMB   1024
#define TPB   256
#define COLS  32          // vocab columns per block = one aligned 128B line per W row
#define CH    256         // emb rows per LDS chunk
#define PITCH 258         // LDS row pitch in floats: write banks 2-way (free), rows 8B-aligned
#define CAP   1024        // match-list capacity (expected ~33 matches/tile)

typedef float f32x4 __attribute__((ext_vector_type(4)));

// out[t, :] = W[:, tokens[t]]  -- inverted: each block owns 32 vocab columns,
// finds its tokens, stages the column block transposed in LDS, streams rows out.
__global__ __launch_bounds__(TPB) void tok_emb_fused(
    const float* __restrict__ W, const int* __restrict__ tokens,
    f32x4* __restrict__ out4, int n_tokens) {
    __shared__ float lds[COLS * PITCH];
    __shared__ int   list[CAP];
    __shared__ int   cnt;

    const int v0  = blockIdx.x * COLS;
    const int tid = threadIdx.x;

    auto run = [&](int lo, int hi) {
        __syncthreads();                 // protect list/cnt from prior readers
        if (tid == 0) cnt = 0;
        __syncthreads();

        // ---- Phase 1: scan tokens in [lo,hi), collect matches for this tile
        const int nvec = (hi - lo) >> 2;
        for (int q = tid; q < nvec; q += TPB) {
            const int4 tk = *reinterpret_cast<const int4*>(&tokens[lo + (q << 2)]);
            const int tv[4] = {tk.x, tk.y, tk.z, tk.w};
#pragma unroll
            for (int jj = 0; jj < 4; ++jj) {
                const unsigned d = (unsigned)(tv[jj] - v0);
                if (d < COLS) {
                    const int p = atomicAdd(&cnt, 1);
                    if (p < CAP) list[p] = ((lo + (q << 2) + jj) << 5) | (int)d;
                }
            }
        }
        for (int i = lo + (nvec << 2) + tid; i < hi; i += TPB) {  // tail
            const unsigned d = (unsigned)(tokens[i] - v0);
            if (d < COLS) {
                const int p = atomicAdd(&cnt, 1);
                if (p < CAP) list[p] = (i << 5) | (int)d;
            }
        }
        __syncthreads();
        const int m = cnt < CAP ? cnt : CAP;   // uniform across block
        if (m == 0) return;

        // ---- Phase 2: per emb-chunk, stage W columns in LDS, write out rows
        for (int c0 = 0; c0 < EMB; c0 += CH) {
            __syncthreads();             // prior chunk's readers done
#pragma unroll
            for (int it = 0; it < (CH * COLS / 4) / TPB; ++it) {  // 8 iters
                const int idx = tid + it * TPB;
                const int r   = idx >> 3;        // emb row in chunk
                const int cc  = (idx & 7) << 2;  // col group of 4
                const float4 v = *reinterpret_cast<const float4*>(
                    &W[(size_t)(c0 + r) * VOCAB + (size_t)(v0 + cc)]);
                lds[(cc + 0) * PITCH + r] = v.x;
                lds[(cc + 1) * PITCH + r] = v.y;
                lds[(cc + 2) * PITCH + r] = v.z;
                lds[(cc + 3) * PITCH + r] = v.w;
            }
            __syncthreads();

            const int total = m << 6;    // m * 64 float4 stores of 256 floats
            for (int j = tid; j < total; j += TPB) {
                const int mi = j >> 6, lane = j & 63;   // mi uniform per wave
                const int ent = list[mi];
                const int t   = ent >> 5, col = ent & 31;
                const float* rp = &lds[col * PITCH + (lane << 2)];
                const float2 a = *reinterpret_cast<const float2*>(rp);
                const float2 b = *reinterpret_cast<const float2*>(rp + 2);
                f32x4 o;
                o.x = a.x; o.y = a.y; o.z = b.x; o.w = b.y;
                __builtin_nontemporal_store(
                    o, &out4[(size_t)t * (EMB / 4) + (c0 >> 2) + lane]);
            }
        }
    };

    run(0, n_tokens);
    __syncthreads();
    if (cnt > CAP) {                      // structural backstop, never taken
        for (int lo = 0; lo < n_tokens; lo += CAP) {  // for uniform-random tokens
            const int hi = (lo + CAP < n_tokens) ? lo + CAP : n_tokens;
            run(lo, hi);
        }
    }
}

extern "C" void kernel_launch(void* const* d_in, const int* in_sizes, int n_in,
                              void* d_out, int out_size, void* d_ws, size_t ws_size,
                              hipStream_t stream) {
    const int*   tokens   = (const int*)d_in[0];   // [8*4096] int32
    const float* W        = (const float*)d_in[1]; // [1024][32000] f32
    f32x4*       out4     = (f32x4*)d_out;         // [32768][1024] f32
    const int    n_tokens = in_sizes[0];

    tok_emb_fused<<<VOCAB / COLS, TPB, 0, stream>>>(W, tokens, out4, n_tokens);
}